// Round 8
// baseline (242.081 us; speedup 1.0000x reference)
//
#include <hip/hip_runtime.h>

#define CH   288
#define GRPS 32
#define CPG  9
#define IMH  64
#define IMW  64
#define HW   4096
#define NB   8
#define NPX  (NB * HW)     // 32768 total pixel rows
#define BN_EPS 1e-5f
#define NSLOT 64
#define NBLK1 (NPX / 32)   // 1024 gemm1 blocks

typedef short bf16x8 __attribute__((ext_vector_type(8)));
typedef float f32x4  __attribute__((ext_vector_type(4)));

// ws layout (bytes)
#define XT_OFF   0u            // x_t / tmp_t bf16 [b][p][c]  (18,874,368 B)
#define WIB_OFF  18874368u     // Wi bf16 [288][288] (plain row-major)
#define WOS_OFF  19040256u     // Wo*scale bf16 [288][288]; ALSO stat slots
                               //   (64 x 576 f32) + counter (u32 @ +147456)
#define SC_OFF   19208448u     // (spare)
#define SH_OFF   19209600u     // (spare)
#define BO2_OFF  19210752u     // folded bias f32 [288]

// gemm1 LDS: two 20480-B buffers (rows 0..31 = X px rows, 32..319 = W rows,
// 64 B per row, XOR chunk swizzle). 40960 B -> 4 blocks/CU.
#define BUF1 20480
// gemm2 LDS: two 22528-B buffers (rows 0..63 = X px rows, 64..351 = W rows).
#define BUF2 22528

__device__ __forceinline__ unsigned short f2b(float f) {
    unsigned int u = __float_as_uint(f);
    return (unsigned short)((u + 0x7fffu + ((u >> 16) & 1u)) >> 16);
}
__device__ __forceinline__ float b2f(unsigned short h) {
    return __uint_as_float(((unsigned int)h) << 16);
}

// async global->LDS, 16B per lane; dst = wave-uniform base + lane*16
#define GLDS(g, l) __builtin_amdgcn_global_load_lds( \
    (const __attribute__((address_space(1))) void*)(g), \
    (__attribute__((address_space(3))) void*)(l), 16, 0, 0)

__device__ __forceinline__ f32x4 mfma16(bf16x8 a, bf16x8 b, f32x4 c) {
    return __builtin_amdgcn_mfma_f32_16x16x32_bf16(a, b, c, 0, 0, 0);
}

// ---------------------------------------------------------------------------
// K0: fused pre-pass.
//  - all blocks: x [b][c][p] f32 -> x_t [b][p][c] bf16 (R5 k_transpose)
//  - blocks (y==0,z==0): zero the 64 stat slots + completion counter
//  - blocks (y==1,z==0): Wi f32 -> Wib bf16 (R5 k_cvt_wi)
// ---------------------------------------------------------------------------
#define TS 40
__global__ __launch_bounds__(256) void k_pre(const float* __restrict__ x,
                                             unsigned short* __restrict__ xt,
                                             const float* __restrict__ Wi,
                                             unsigned short* __restrict__ Wib,
                                             float* __restrict__ slots) {
    __shared__ unsigned short T[64 * TS];
    const int tid = threadIdx.x;
    const int p0 = blockIdx.x * 64;
    const int c0 = blockIdx.y * 32;
    const int b  = blockIdx.z;

    if (blockIdx.z == 0) {
        if (blockIdx.y == 0) {
            // zero slots (36864 f32) + counter (1 u32, same region)
            for (int i = blockIdx.x * 256 + tid; i < NSLOT * 576 + 1; i += 64 * 256)
                slots[i] = 0.0f;
        } else if (blockIdx.y == 1) {
            // Wi cvt: 20736 items of 4 floats
            for (int i = blockIdx.x * 256 + tid; i < CH * CH / 4; i += 64 * 256) {
                const float4 v = ((const float4*)Wi)[i];
                unsigned short h[4] = {f2b(v.x), f2b(v.y), f2b(v.z), f2b(v.w)};
                *(uint2*)(Wib + (size_t)i * 4) = *(const uint2*)h;
            }
        }
    }

    #pragma unroll
    for (int it = 0; it < 2; ++it) {
        const int item  = it * 256 + tid;
        const int c_loc = item >> 4;
        const int p4    = item & 15;
        const float4 v = *(const float4*)(x + (size_t)(b * CH + c0 + c_loc) * HW + p0 + p4 * 4);
        const int px = p4 * 4;
        T[(px + 0) * TS + c_loc] = f2b(v.x);
        T[(px + 1) * TS + c_loc] = f2b(v.y);
        T[(px + 2) * TS + c_loc] = f2b(v.z);
        T[(px + 3) * TS + c_loc] = f2b(v.w);
    }
    __syncthreads();
    const int px_loc = tid >> 2;
    const int cq     = tid & 3;
    const uint4 o = *(const uint4*)((const char*)T + px_loc * (TS * 2) + cq * 16);
    *(uint4*)(xt + ((size_t)b * HW + p0 + px_loc) * CH + c0 + cq * 8) = o;
}

// ---------------------------------------------------------------------------
// K1: pipelined MFMA GEMM1 + fused BN stats (R5-proven core) + last-block
// tail that computes BN scale/shift AND the Wo fold (Wos, bo2) in-kernel.
// Block: 32 px x 288 c, 4 waves; wave = 16 px x 144 c (acc[9]).
// Double-buffered BK=32, counted vmcnt; 4 blocks/CU.
// ---------------------------------------------------------------------------
__global__ __launch_bounds__(256, 4) void k_gemm1(const unsigned short* __restrict__ Wib,
                                                  const float* __restrict__ bi,
                                                  unsigned short* __restrict__ xt,
                                                  float* __restrict__ slots,
                                                  const float* __restrict__ gamma,
                                                  const float* __restrict__ beta,
                                                  const float* __restrict__ Wo,
                                                  const float* __restrict__ bo,
                                                  unsigned short* __restrict__ Wos,
                                                  float* __restrict__ bo2) {
    __shared__ char smc[2 * BUF1];   // 40960 B
    __shared__ int lastFlag;

    const int tid  = threadIdx.x;
    const int wave = tid >> 6;
    const int lane = tid & 63;
    const int q    = lane >> 4;
    const int r    = lane & 15;
    const int pxh  = wave & 1;      // 16-px half
    const int chh  = wave >> 1;     // 144-c half
    const int p0   = blockIdx.x * 32;
    const int lrow = lane >> 2;
    const int lp   = lane & 3;

    f32x4 acc[9];
    #pragma unroll
    for (int j = 0; j < 9; ++j) acc[j] = (f32x4)0.0f;

    const unsigned short* xsrc = xt + (size_t)p0 * CH;

    // stage one BK=32 slice: 20 x 1KB segments (2 X + 18 W), 5 GLDS/wave
    #define STAGE1(K0v, DST) do {                                              \
        for (int s = wave; s < 20; s += 4) {                                   \
            const int row = s * 16 + lrow;                                     \
            const int sc  = lp ^ ((row >> 1) & 3);                             \
            const unsigned short* g = (s < 2)                                  \
                ? xsrc + (size_t)row * CH + (K0v) + sc * 8                     \
                : Wib  + (size_t)(row - 32) * CH + (K0v) + sc * 8;             \
            GLDS(g, (DST) + s * 1024);                                         \
        }                                                                      \
    } while (0)

    #define GSTEP1(BUF) do {                                                   \
        const int xr = pxh * 16 + r;                                           \
        const bf16x8 xf = *(const bf16x8*)((BUF) + xr * 64 +                   \
                             ((q ^ ((xr >> 1) & 3)) * 16));                    \
        _Pragma("unroll")                                                      \
        for (int j = 0; j < 9; ++j) {                                          \
            const int wr = 32 + chh * 144 + j * 16 + r;                        \
            const bf16x8 wf = *(const bf16x8*)((BUF) + wr * 64 +               \
                                 ((q ^ ((wr >> 1) & 3)) * 16));                \
            acc[j] = mfma16(wf, xf, acc[j]);                                   \
        }                                                                      \
    } while (0)

    STAGE1(0, smc);
    asm volatile("s_waitcnt vmcnt(0)" ::: "memory");
    __builtin_amdgcn_s_barrier();
    #pragma unroll 1
    for (int kk = 0; kk < 8; ++kk) {
        STAGE1((kk + 1) * 32, smc + ((kk + 1) & 1) * BUF1);
        asm volatile("s_waitcnt vmcnt(5)" ::: "memory");
        __builtin_amdgcn_s_barrier();
        GSTEP1(smc + (kk & 1) * BUF1);
        __builtin_amdgcn_s_barrier();
    }
    asm volatile("s_waitcnt vmcnt(0)" ::: "memory");
    __builtin_amdgcn_s_barrier();
    GSTEP1(smc);
    __syncthreads();

    // ================= epilogue =================
    // LDS reuse: [0, 18432) = 32 rows x 576 B output staging,
    //            [38656, 40960) = 576-float stats accumulator.
    float* sstat = (float*)(smc + 38656);
    for (int c2 = tid; c2 < 576; c2 += 256) sstat[c2] = 0.0f;
    __syncthreads();

    #pragma unroll 1
    for (int j = 0; j < 9; ++j) {
        const int cb = chh * 144 + j * 16 + q * 4;
        const float4 b4 = *(const float4*)(bi + cb);
        float v[4];
        v[0] = fmaxf(acc[j][0] + b4.x, 0.0f);
        v[1] = fmaxf(acc[j][1] + b4.y, 0.0f);
        v[2] = fmaxf(acc[j][2] + b4.z, 0.0f);
        v[3] = fmaxf(acc[j][3] + b4.w, 0.0f);
        unsigned short h[4] = {f2b(v[0]), f2b(v[1]), f2b(v[2]), f2b(v[3])};
        *(uint2*)(smc + (pxh * 16 + r) * 576 + cb * 2) = *(const uint2*)h;
        float a1[4] = {v[0], v[1], v[2], v[3]};
        float a2[4] = {v[0]*v[0], v[1]*v[1], v[2]*v[2], v[3]*v[3]};
        #pragma unroll
        for (int m = 1; m < 16; m <<= 1) {
            #pragma unroll
            for (int i = 0; i < 4; ++i) {
                a1[i] += __shfl_xor(a1[i], m, 64);
                a2[i] += __shfl_xor(a2[i], m, 64);
            }
        }
        if (r == 0) {
            #pragma unroll
            for (int i = 0; i < 4; ++i) {
                atomicAdd(&sstat[cb + i], a1[i]);
                atomicAdd(&sstat[288 + cb + i], a2[i]);
            }
        }
    }
    __syncthreads();

    // ---- coalesced store of the 32x288 bf16 tile + slotted stats flush ----
    for (int idx = tid; idx < 1152; idx += 256) {
        const int row = idx / 36;
        const int off = idx - row * 36;
        *(uint4*)(xt + (size_t)(p0 + row) * CH + off * 8) =
            *(const uint4*)(smc + row * 576 + off * 16);
    }
    float* slot = slots + (size_t)(blockIdx.x & (NSLOT - 1)) * 576;
    for (int c2 = tid; c2 < 576; c2 += 256)
        atomicAdd(&slot[c2], sstat[c2]);

    // ================= last-block tail: BN scale/shift + Wo fold ===========
    unsigned int* counter = (unsigned int*)(slots + NSLOT * 576);
    if (tid == 0) {
        __threadfence();
        const unsigned int old = atomicAdd(counter, 1u);
        lastFlag = (old == (unsigned int)(NBLK1 - 1));
    }
    __syncthreads();
    if (!lastFlag) return;
    __threadfence();

    float* sumL   = (float*)(smc + 8192);   // 576 f32
    float* scaleL = (float*)(smc);          // 288 f32
    float* shiftL = (float*)(smc + 2048);   // 288 f32

    // reduce the 64 slots (atomic reads: cross-XCD-coherent, G16)
    for (int c = tid; c < 576; c += 256) {
        float s = 0.0f;
        #pragma unroll 8
        for (int sl = 0; sl < NSLOT; ++sl)
            s += atomicAdd(&slots[sl * 576 + c], 0.0f);
        sumL[c] = s;
    }
    __syncthreads();
    for (int c = tid; c < CH; c += 256) {
        const float inv  = 1.0f / (float)(NB * HW);
        const float mean = sumL[c] * inv;
        const float var  = sumL[288 + c] * inv - mean * mean;
        const float rs   = rsqrtf(var + BN_EPS);
        const float sc   = gamma[c] * rs;
        scaleL[c] = sc;
        shiftL[c] = beta[c] - mean * sc;
    }
    __syncthreads();
    // bo2[m] = bo[m] + Wo[m][:] @ shift
    for (int m = tid; m < CH; m += 256) {
        float s = bo[m];
        #pragma unroll 8
        for (int k = 0; k < CH; ++k) s += Wo[(size_t)m * CH + k] * shiftL[k];
        bo2[m] = s;
    }
    // Wos[m][k] = bf16(Wo[m][k] * scale[k])  (plain row-major; overwrites slots)
    for (int id = tid; id < CH * 36; id += 256) {
        const int m  = id / 36;
        const int c0 = (id - m * 36) * 8;
        const float4 a = *(const float4*)(Wo + (size_t)m * CH + c0);
        const float4 b = *(const float4*)(Wo + (size_t)m * CH + c0 + 4);
        unsigned short h[8] = {
            f2b(a.x * scaleL[c0 + 0]), f2b(a.y * scaleL[c0 + 1]),
            f2b(a.z * scaleL[c0 + 2]), f2b(a.w * scaleL[c0 + 3]),
            f2b(b.x * scaleL[c0 + 4]), f2b(b.y * scaleL[c0 + 5]),
            f2b(b.z * scaleL[c0 + 6]), f2b(b.w * scaleL[c0 + 7])};
        *(uint4*)(Wos + (size_t)m * CH + c0) = *(const uint4*)h;
    }
}

// ---------------------------------------------------------------------------
// K3: pipelined MFMA GEMM2 (ker = Wos @ tmp + bo2) -> kerL -> involution.
// Block: 64 px (one image row) x 288 ker-ch, 4 waves; wave = 32 px x 144 c.
// Double-buffered BK=32, counted vmcnt (6/6/5/5 per wave).  [R5 verbatim]
// ---------------------------------------------------------------------------
#define KLS2 68
__global__ __launch_bounds__(256) void k_gemm2_invol(const unsigned short* __restrict__ xt,
                                                     const unsigned short* __restrict__ Wos,
                                                     const float* __restrict__ bo2,
                                                     const float* __restrict__ x,
                                                     float* __restrict__ out) {
    __shared__ char smc[2 * BUF2];   // 45056 B; kerL reuses [0, 39168)
    unsigned short* kerL = (unsigned short*)smc;

    const int tid  = threadIdx.x;
    const int wave = tid >> 6;
    const int lane = tid & 63;
    const int q    = lane >> 4;
    const int r    = lane & 15;
    const int pxh  = wave & 1;
    const int chh  = wave >> 1;
    const int p0   = blockIdx.x * 64;    // 64 px = one full image row
    const int b    = blockIdx.y;
    const int h    = blockIdx.x;
    const size_t rowbase = (size_t)b * HW + p0;
    const int lrow = lane >> 2;
    const int lp   = lane & 3;

    f32x4 acc[2][9];
    #pragma unroll
    for (int t = 0; t < 2; ++t)
        #pragma unroll
        for (int j = 0; j < 9; ++j) acc[t][j] = (f32x4)0.0f;

    const unsigned short* xsrc = xt + rowbase * CH;

    #define STAGE2(K0v, DST) do {                                              \
        for (int s = wave; s < 22; s += 4) {                                   \
            const int row = s * 16 + lrow;                                     \
            const int sc  = lp ^ ((row >> 1) & 3);                             \
            const unsigned short* g = (s < 4)                                  \
                ? xsrc + (size_t)row * CH + (K0v) + sc * 8                     \
                : Wos  + (size_t)(row - 64) * CH + (K0v) + sc * 8;             \
            GLDS(g, (DST) + s * 1024);                                         \
        }                                                                      \
    } while (0)

    #define GSTEP2(BUF) do {                                                   \
        bf16x8 xf0, xf1;                                                       \
        { const int xr = pxh * 32 + r;                                         \
          xf0 = *(const bf16x8*)((BUF) + xr * 64 +                             \
                     ((q ^ ((xr >> 1) & 3)) * 16)); }                          \
        { const int xr = pxh * 32 + 16 + r;                                    \
          xf1 = *(const bf16x8*)((BUF) + xr * 64 +                             \
                     ((q ^ ((xr >> 1) & 3)) * 16)); }                          \
        _Pragma("unroll")                                                      \
        for (int j = 0; j < 9; ++j) {                                          \
            const int wr = 64 + chh * 144 + j * 16 + r;                        \
            const bf16x8 wf = *(const bf16x8*)((BUF) + wr * 64 +               \
                                 ((q ^ ((wr >> 1) & 3)) * 16));                \
            acc[0][j] = mfma16(wf, xf0, acc[0][j]);                            \
            acc[1][j] = mfma16(wf, xf1, acc[1][j]);                            \
        }                                                                      \
    } while (0)

    STAGE2(0, smc);
    asm volatile("s_waitcnt vmcnt(0)" ::: "memory");
    __builtin_amdgcn_s_barrier();
    #pragma unroll 1
    for (int kk = 0; kk < 8; ++kk) {
        STAGE2((kk + 1) * 32, smc + ((kk + 1) & 1) * BUF2);
        if (wave < 2) { asm volatile("s_waitcnt vmcnt(6)" ::: "memory"); }
        else          { asm volatile("s_waitcnt vmcnt(5)" ::: "memory"); }
        __builtin_amdgcn_s_barrier();
        GSTEP2(smc + (kk & 1) * BUF2);
        __builtin_amdgcn_s_barrier();
    }
    asm volatile("s_waitcnt vmcnt(0)" ::: "memory");
    __builtin_amdgcn_s_barrier();
    GSTEP2(smc);
    __syncthreads();

    // ---- stage ker tile to LDS: kerL[ch][px], 288 x 64 (stride 68) ----
    #pragma unroll
    for (int j = 0; j < 9; ++j) {
        const int cb = chh * 144 + j * 16 + q * 4;
        const float4 bz = *(const float4*)(bo2 + cb);
        #pragma unroll
        for (int t = 0; t < 2; ++t) {
            const int pxl = pxh * 32 + t * 16 + r;
            kerL[(cb + 0) * KLS2 + pxl] = f2b(acc[t][j][0] + bz.x);
            kerL[(cb + 1) * KLS2 + pxl] = f2b(acc[t][j][1] + bz.y);
            kerL[(cb + 2) * KLS2 + pxl] = f2b(acc[t][j][2] + bz.z);
            kerL[(cb + 3) * KLS2 + pxl] = f2b(acc[t][j][3] + bz.w);
        }
    }
    __syncthreads();

    // ---- involution: 256 threads, 16 ch x 64 w per iteration, 18 iters ----
    const int tm = tid >> 4;
    const int tn = tid & 15;
    const int wb = tn * 4;
    #pragma unroll 1
    for (int i = 0; i < 18; ++i) {
        const int ch = tm + 16 * i;
        const int cb = (ch / CPG) * CPG;
        float xv[3][6];
        #pragma unroll
        for (int dr = 0; dr < 3; ++dr) {
            const int hh = h + dr - 1;
            const bool rv = (hh >= 0) && (hh < IMH);
            const float* xr2 = x + ((size_t)(b * CH + ch) * IMH + (rv ? hh : 0)) * IMW;
            if (rv) {
                const float4 m4 = *(const float4*)(xr2 + wb);
                xv[dr][1] = m4.x; xv[dr][2] = m4.y; xv[dr][3] = m4.z; xv[dr][4] = m4.w;
                xv[dr][0] = (wb > 0)       ? xr2[wb - 1] : 0.0f;
                xv[dr][5] = (wb + 4 < IMW) ? xr2[wb + 4] : 0.0f;
            } else {
                #pragma unroll
                for (int j = 0; j < 6; ++j) xv[dr][j] = 0.0f;
            }
        }
        float o[4] = {0.0f, 0.0f, 0.0f, 0.0f};
        #pragma unroll
        for (int k = 0; k < 9; ++k) {
            const int dr = k / 3, dc = k % 3;
            const uint2 kk = *(const uint2*)(kerL + (cb + k) * KLS2 + tn * 4);
            const unsigned short* ks = (const unsigned short*)&kk;
            #pragma unroll
            for (int j = 0; j < 4; ++j)
                o[j] += b2f(ks[j]) * xv[dr][j + dc];
        }
        float4 ov = {o[0], o[1], o[2], o[3]};
        *(float4*)(out + ((size_t)(b * CH + ch) * IMH + h) * IMW + wb) = ov;
    }
}

// ---------------------------------------------------------------------------
extern "C" void kernel_launch(void* const* d_in, const int* in_sizes, int n_in,
                              void* d_out, int out_size, void* d_ws, size_t ws_size,
                              hipStream_t stream) {
    const float* x     = (const float*)d_in[0];
    const float* Wi    = (const float*)d_in[1];
    const float* bi    = (const float*)d_in[2];
    const float* gamma = (const float*)d_in[3];
    const float* beta  = (const float*)d_in[4];
    const float* Wo    = (const float*)d_in[5];
    const float* bo    = (const float*)d_in[6];
    float* out = (float*)d_out;

    char* ws = (char*)d_ws;
    unsigned short* xt  = (unsigned short*)(ws + XT_OFF);
    unsigned short* Wib = (unsigned short*)(ws + WIB_OFF);
    unsigned short* Wos = (unsigned short*)(ws + WOS_OFF);
    float* slots = (float*)(ws + WOS_OFF);      // stat slots + counter, pre-fold
    float* bo2   = (float*)(ws + BO2_OFF);

    k_pre<<<dim3(HW / 64, CH / 32, NB), 256, 0, stream>>>(x, xt, Wi, Wib, slots);
    k_gemm1<<<dim3(NBLK1), 256, 0, stream>>>(Wib, bi, xt, slots,
                                             gamma, beta, Wo, bo, Wos, bo2);
    k_gemm2_invol<<<dim3(HW / 64, NB), 256, 0, stream>>>(xt, Wos, bo2, x, out);
}

// Round 9
// 209.262 us; speedup vs baseline: 1.1568x; 1.1568x over previous
//
#include <hip/hip_runtime.h>

#define CH   288
#define GRPS 32
#define CPG  9
#define IMH  64
#define IMW  64
#define HW   4096
#define NB   8
#define NPX  (NB * HW)     // 32768 total pixel rows
#define BN_EPS 1e-5f
#define NSLOT 64
#define NBLK1 (NPX / 32)   // 1024 gemm1 blocks

typedef short bf16x8 __attribute__((ext_vector_type(8)));
typedef float f32x4  __attribute__((ext_vector_type(4)));

// ws layout (bytes)
#define XT_OFF   0u            // x_t / tmp_t bf16 [b][p][c]  (18,874,368 B)
#define WIB_OFF  18874368u     // Wi bf16 [288][288] (plain row-major)
#define WOS_OFF  19040256u     // Wo*scale bf16 [288][288]; ALSO stat slots
                               //   (64 x 576 f32) + counter (u32 @ +147456)
#define BO2_OFF  19210752u     // folded bias f32 [288]

// gemm1 LDS: two 20480-B buffers (rows 0..31 = X px rows, 32..319 = W rows,
// 64 B per row, XOR chunk swizzle). EXACTLY 40960 B -> 4 blocks/CU (160 KiB).
// NO other __shared__ allowed in this kernel (R8 lesson: +4 B -> 41472 -> 3/CU).
#define BUF1 20480
// gemm2 LDS: two 22528-B buffers (rows 0..63 = X px rows, 64..351 = W rows).
#define BUF2 22528

__device__ __forceinline__ unsigned short f2b(float f) {
    unsigned int u = __float_as_uint(f);
    return (unsigned short)((u + 0x7fffu + ((u >> 16) & 1u)) >> 16);
}
__device__ __forceinline__ float b2f(unsigned short h) {
    return __uint_as_float(((unsigned int)h) << 16);
}

// async global->LDS, 16B per lane; dst = wave-uniform base + lane*16
#define GLDS(g, l) __builtin_amdgcn_global_load_lds( \
    (const __attribute__((address_space(1))) void*)(g), \
    (__attribute__((address_space(3))) void*)(l), 16, 0, 0)

__device__ __forceinline__ f32x4 mfma16(bf16x8 a, bf16x8 b, f32x4 c) {
    return __builtin_amdgcn_mfma_f32_16x16x32_bf16(a, b, c, 0, 0, 0);
}

// ---------------------------------------------------------------------------
// K0: fused pre-pass.
//  - all blocks: x [b][c][p] f32 -> x_t [b][p][c] bf16
//  - blocks (y==0,z==0): zero the 64 stat slots + completion counter
//  - blocks (y==1,z==0): Wi f32 -> Wib bf16
// ---------------------------------------------------------------------------
#define TS 40
__global__ __launch_bounds__(256) void k_pre(const float* __restrict__ x,
                                             unsigned short* __restrict__ xt,
                                             const float* __restrict__ Wi,
                                             unsigned short* __restrict__ Wib,
                                             float* __restrict__ slots) {
    __shared__ unsigned short T[64 * TS];
    const int tid = threadIdx.x;
    const int p0 = blockIdx.x * 64;
    const int c0 = blockIdx.y * 32;
    const int b  = blockIdx.z;

    if (blockIdx.z == 0) {
        if (blockIdx.y == 0) {
            for (int i = blockIdx.x * 256 + tid; i < NSLOT * 576 + 1; i += 64 * 256)
                slots[i] = 0.0f;
        } else if (blockIdx.y == 1) {
            for (int i = blockIdx.x * 256 + tid; i < CH * CH / 4; i += 64 * 256) {
                const float4 v = ((const float4*)Wi)[i];
                unsigned short h[4] = {f2b(v.x), f2b(v.y), f2b(v.z), f2b(v.w)};
                *(uint2*)(Wib + (size_t)i * 4) = *(const uint2*)h;
            }
        }
    }

    #pragma unroll
    for (int it = 0; it < 2; ++it) {
        const int item  = it * 256 + tid;
        const int c_loc = item >> 4;
        const int p4    = item & 15;
        const float4 v = *(const float4*)(x + (size_t)(b * CH + c0 + c_loc) * HW + p0 + p4 * 4);
        const int px = p4 * 4;
        T[(px + 0) * TS + c_loc] = f2b(v.x);
        T[(px + 1) * TS + c_loc] = f2b(v.y);
        T[(px + 2) * TS + c_loc] = f2b(v.z);
        T[(px + 3) * TS + c_loc] = f2b(v.w);
    }
    __syncthreads();
    const int px_loc = tid >> 2;
    const int cq     = tid & 3;
    const uint4 o = *(const uint4*)((const char*)T + px_loc * (TS * 2) + cq * 16);
    *(uint4*)(xt + ((size_t)b * HW + p0 + px_loc) * CH + c0 + cq * 8) = o;
}

// ---------------------------------------------------------------------------
// K1: pipelined MFMA GEMM1 + fused BN stats (R5-proven core) + last-block
// tail (BN scale/shift + Wo fold). NO threadfence (L2-writeback-free:
// ordering via vmcnt(0) + device-scope atomics only). LDS exactly 40960.
// Block: 32 px x 288 c, 4 waves; wave = 16 px x 144 c (acc[9]).
// ---------------------------------------------------------------------------
__global__ __launch_bounds__(256, 4) void k_gemm1(const unsigned short* __restrict__ Wib,
                                                  const float* __restrict__ bi,
                                                  unsigned short* __restrict__ xt,
                                                  float* __restrict__ slots,
                                                  const float* __restrict__ gamma,
                                                  const float* __restrict__ beta,
                                                  const float* __restrict__ Wo,
                                                  const float* __restrict__ bo,
                                                  unsigned short* __restrict__ Wos,
                                                  float* __restrict__ bo2) {
    __shared__ char smc[2 * BUF1];   // 40960 B — the ONLY shared allocation

    const int tid  = threadIdx.x;
    const int wave = tid >> 6;
    const int lane = tid & 63;
    const int q    = lane >> 4;
    const int r    = lane & 15;
    const int pxh  = wave & 1;      // 16-px half
    const int chh  = wave >> 1;     // 144-c half
    const int p0   = blockIdx.x * 32;
    const int lrow = lane >> 2;
    const int lp   = lane & 3;

    f32x4 acc[9];
    #pragma unroll
    for (int j = 0; j < 9; ++j) acc[j] = (f32x4)0.0f;

    const unsigned short* xsrc = xt + (size_t)p0 * CH;

    // stage one BK=32 slice: 20 x 1KB segments (2 X + 18 W), 5 GLDS/wave
    #define STAGE1(K0v, DST) do {                                              \
        for (int s = wave; s < 20; s += 4) {                                   \
            const int row = s * 16 + lrow;                                     \
            const int sc  = lp ^ ((row >> 1) & 3);                             \
            const unsigned short* g = (s < 2)                                  \
                ? xsrc + (size_t)row * CH + (K0v) + sc * 8                     \
                : Wib  + (size_t)(row - 32) * CH + (K0v) + sc * 8;             \
            GLDS(g, (DST) + s * 1024);                                         \
        }                                                                      \
    } while (0)

    #define GSTEP1(BUF) do {                                                   \
        const int xr = pxh * 16 + r;                                           \
        const bf16x8 xf = *(const bf16x8*)((BUF) + xr * 64 +                   \
                             ((q ^ ((xr >> 1) & 3)) * 16));                    \
        _Pragma("unroll")                                                      \
        for (int j = 0; j < 9; ++j) {                                          \
            const int wr = 32 + chh * 144 + j * 16 + r;                        \
            const bf16x8 wf = *(const bf16x8*)((BUF) + wr * 64 +               \
                                 ((q ^ ((wr >> 1) & 3)) * 16));                \
            acc[j] = mfma16(wf, xf, acc[j]);                                   \
        }                                                                      \
    } while (0)

    STAGE1(0, smc);
    asm volatile("s_waitcnt vmcnt(0)" ::: "memory");
    __builtin_amdgcn_s_barrier();
    #pragma unroll 1
    for (int kk = 0; kk < 8; ++kk) {
        STAGE1((kk + 1) * 32, smc + ((kk + 1) & 1) * BUF1);
        asm volatile("s_waitcnt vmcnt(5)" ::: "memory");
        __builtin_amdgcn_s_barrier();
        GSTEP1(smc + (kk & 1) * BUF1);
        __builtin_amdgcn_s_barrier();
    }
    asm volatile("s_waitcnt vmcnt(0)" ::: "memory");
    __builtin_amdgcn_s_barrier();
    GSTEP1(smc);
    __syncthreads();

    // ================= epilogue =================
    // LDS reuse: [0, 18432) = 32 rows x 576 B output staging,
    //            [38656, 40960) = 576-float stats accumulator.
    float* sstat = (float*)(smc + 38656);
    for (int c2 = tid; c2 < 576; c2 += 256) sstat[c2] = 0.0f;
    __syncthreads();

    #pragma unroll 1
    for (int j = 0; j < 9; ++j) {
        const int cb = chh * 144 + j * 16 + q * 4;
        const float4 b4 = *(const float4*)(bi + cb);
        float v[4];
        v[0] = fmaxf(acc[j][0] + b4.x, 0.0f);
        v[1] = fmaxf(acc[j][1] + b4.y, 0.0f);
        v[2] = fmaxf(acc[j][2] + b4.z, 0.0f);
        v[3] = fmaxf(acc[j][3] + b4.w, 0.0f);
        unsigned short h[4] = {f2b(v[0]), f2b(v[1]), f2b(v[2]), f2b(v[3])};
        *(uint2*)(smc + (pxh * 16 + r) * 576 + cb * 2) = *(const uint2*)h;
        float a1[4] = {v[0], v[1], v[2], v[3]};
        float a2[4] = {v[0]*v[0], v[1]*v[1], v[2]*v[2], v[3]*v[3]};
        #pragma unroll
        for (int m = 1; m < 16; m <<= 1) {
            #pragma unroll
            for (int i = 0; i < 4; ++i) {
                a1[i] += __shfl_xor(a1[i], m, 64);
                a2[i] += __shfl_xor(a2[i], m, 64);
            }
        }
        if (r == 0) {
            #pragma unroll
            for (int i = 0; i < 4; ++i) {
                atomicAdd(&sstat[cb + i], a1[i]);
                atomicAdd(&sstat[288 + cb + i], a2[i]);
            }
        }
    }
    __syncthreads();

    // ---- coalesced store of the 32x288 bf16 tile + slotted stats flush ----
    for (int idx = tid; idx < 1152; idx += 256) {
        const int row = idx / 36;
        const int off = idx - row * 36;
        *(uint4*)(xt + (size_t)(p0 + row) * CH + off * 8) =
            *(const uint4*)(smc + row * 576 + off * 16);
    }
    float* slot = slots + (size_t)(blockIdx.x & (NSLOT - 1)) * 576;
    for (int c2 = tid; c2 < 576; c2 += 256)
        atomicAdd(&slot[c2], sstat[c2]);

    // ================= last-block tail: BN scale/shift + Wo fold ===========
    // lastFlag lives INSIDE smc (offset 20480, dead here) — LDS stays 40960.
    int* lastFlag = (int*)(smc + 20480);
    unsigned int* counter = (unsigned int*)(slots + NSLOT * 576);
    if (tid == 0) {
        // order: slot atomics retired (coherence point) before counter bump.
        asm volatile("s_waitcnt vmcnt(0)" ::: "memory");
        const unsigned int old = atomicAdd(counter, 1u);
        *lastFlag = (old == (unsigned int)(NBLK1 - 1));
    }
    __syncthreads();
    if (!*lastFlag) return;

    float* sumL   = (float*)(smc + 8192);   // 576 f32
    float* scaleL = (float*)(smc);          // 288 f32
    float* shiftL = (float*)(smc + 2048);   // 288 f32

    // reduce the 64 slots (atomic reads: device-scope coherent, G16)
    for (int c = tid; c < 576; c += 256) {
        float s = 0.0f;
        #pragma unroll 8
        for (int sl = 0; sl < NSLOT; ++sl)
            s += atomicAdd(&slots[sl * 576 + c], 0.0f);
        sumL[c] = s;
    }
    __syncthreads();
    for (int c = tid; c < CH; c += 256) {
        const float inv  = 1.0f / (float)(NB * HW);
        const float mean = sumL[c] * inv;
        const float var  = sumL[288 + c] * inv - mean * mean;
        const float rs   = rsqrtf(var + BN_EPS);
        const float sc   = gamma[c] * rs;
        scaleL[c] = sc;
        shiftL[c] = beta[c] - mean * sc;
    }
    __syncthreads();
    // bo2[m] = bo[m] + Wo[m][:] @ shift
    for (int m = tid; m < CH; m += 256) {
        float s = bo[m];
        #pragma unroll 8
        for (int k = 0; k < CH; ++k) s += Wo[(size_t)m * CH + k] * shiftL[k];
        bo2[m] = s;
    }
    // Wos[m][k] = bf16(Wo[m][k] * scale[k])  (row-major; overwrites slots)
    for (int id = tid; id < CH * 36; id += 256) {
        const int m  = id / 36;
        const int c0 = (id - m * 36) * 8;
        const float4 a = *(const float4*)(Wo + (size_t)m * CH + c0);
        const float4 b = *(const float4*)(Wo + (size_t)m * CH + c0 + 4);
        unsigned short h[8] = {
            f2b(a.x * scaleL[c0 + 0]), f2b(a.y * scaleL[c0 + 1]),
            f2b(a.z * scaleL[c0 + 2]), f2b(a.w * scaleL[c0 + 3]),
            f2b(b.x * scaleL[c0 + 4]), f2b(b.y * scaleL[c0 + 5]),
            f2b(b.z * scaleL[c0 + 6]), f2b(b.w * scaleL[c0 + 7])};
        *(uint4*)(Wos + (size_t)m * CH + c0) = *(const uint4*)h;
    }
}

// ---------------------------------------------------------------------------
// K3: pipelined MFMA GEMM2 (ker = Wos @ tmp + bo2) -> kerL -> involution.
// Block: 64 px (one image row) x 288 ker-ch, 4 waves; wave = 32 px x 144 c.
// Double-buffered BK=32, counted vmcnt (6/6/5/5 per wave).  [R5 verbatim]
// ---------------------------------------------------------------------------
#define KLS2 68
__global__ __launch_bounds__(256) void k_gemm2_invol(const unsigned short* __restrict__ xt,
                                                     const unsigned short* __restrict__ Wos,
                                                     const float* __restrict__ bo2,
                                                     const float* __restrict__ x,
                                                     float* __restrict__ out) {
    __shared__ char smc[2 * BUF2];   // 45056 B; kerL reuses [0, 39168)
    unsigned short* kerL = (unsigned short*)smc;

    const int tid  = threadIdx.x;
    const int wave = tid >> 6;
    const int lane = tid & 63;
    const int q    = lane >> 4;
    const int r    = lane & 15;
    const int pxh  = wave & 1;
    const int chh  = wave >> 1;
    const int p0   = blockIdx.x * 64;    // 64 px = one full image row
    const int b    = blockIdx.y;
    const int h    = blockIdx.x;
    const size_t rowbase = (size_t)b * HW + p0;
    const int lrow = lane >> 2;
    const int lp   = lane & 3;

    f32x4 acc[2][9];
    #pragma unroll
    for (int t = 0; t < 2; ++t)
        #pragma unroll
        for (int j = 0; j < 9; ++j) acc[t][j] = (f32x4)0.0f;

    const unsigned short* xsrc = xt + rowbase * CH;

    #define STAGE2(K0v, DST) do {                                              \
        for (int s = wave; s < 22; s += 4) {                                   \
            const int row = s * 16 + lrow;                                     \
            const int sc  = lp ^ ((row >> 1) & 3);                             \
            const unsigned short* g = (s < 4)                                  \
                ? xsrc + (size_t)row * CH + (K0v) + sc * 8                     \
                : Wos  + (size_t)(row - 64) * CH + (K0v) + sc * 8;             \
            GLDS(g, (DST) + s * 1024);                                         \
        }                                                                      \
    } while (0)

    #define GSTEP2(BUF) do {                                                   \
        bf16x8 xf0, xf1;                                                       \
        { const int xr = pxh * 32 + r;                                         \
          xf0 = *(const bf16x8*)((BUF) + xr * 64 +                             \
                     ((q ^ ((xr >> 1) & 3)) * 16)); }                          \
        { const int xr = pxh * 32 + 16 + r;                                    \
          xf1 = *(const bf16x8*)((BUF) + xr * 64 +                             \
                     ((q ^ ((xr >> 1) & 3)) * 16)); }                          \
        _Pragma("unroll")                                                      \
        for (int j = 0; j < 9; ++j) {                                          \
            const int wr = 64 + chh * 144 + j * 16 + r;                        \
            const bf16x8 wf = *(const bf16x8*)((BUF) + wr * 64 +               \
                                 ((q ^ ((wr >> 1) & 3)) * 16));                \
            acc[0][j] = mfma16(wf, xf0, acc[0][j]);                            \
            acc[1][j] = mfma16(wf, xf1, acc[1][j]);                            \
        }                                                                      \
    } while (0)

    STAGE2(0, smc);
    asm volatile("s_waitcnt vmcnt(0)" ::: "memory");
    __builtin_amdgcn_s_barrier();
    #pragma unroll 1
    for (int kk = 0; kk < 8; ++kk) {
        STAGE2((kk + 1) * 32, smc + ((kk + 1) & 1) * BUF2);
        if (wave < 2) { asm volatile("s_waitcnt vmcnt(6)" ::: "memory"); }
        else          { asm volatile("s_waitcnt vmcnt(5)" ::: "memory"); }
        __builtin_amdgcn_s_barrier();
        GSTEP2(smc + (kk & 1) * BUF2);
        __builtin_amdgcn_s_barrier();
    }
    asm volatile("s_waitcnt vmcnt(0)" ::: "memory");
    __builtin_amdgcn_s_barrier();
    GSTEP2(smc);
    __syncthreads();

    // ---- stage ker tile to LDS: kerL[ch][px], 288 x 64 (stride 68) ----
    #pragma unroll
    for (int j = 0; j < 9; ++j) {
        const int cb = chh * 144 + j * 16 + q * 4;
        const float4 bz = *(const float4*)(bo2 + cb);
        #pragma unroll
        for (int t = 0; t < 2; ++t) {
            const int pxl = pxh * 32 + t * 16 + r;
            kerL[(cb + 0) * KLS2 + pxl] = f2b(acc[t][j][0] + bz.x);
            kerL[(cb + 1) * KLS2 + pxl] = f2b(acc[t][j][1] + bz.y);
            kerL[(cb + 2) * KLS2 + pxl] = f2b(acc[t][j][2] + bz.z);
            kerL[(cb + 3) * KLS2 + pxl] = f2b(acc[t][j][3] + bz.w);
        }
    }
    __syncthreads();

    // ---- involution: 256 threads, 16 ch x 64 w per iteration, 18 iters ----
    const int tm = tid >> 4;
    const int tn = tid & 15;
    const int wb = tn * 4;
    #pragma unroll 1
    for (int i = 0; i < 18; ++i) {
        const int ch = tm + 16 * i;
        const int cb = (ch / CPG) * CPG;
        float xv[3][6];
        #pragma unroll
        for (int dr = 0; dr < 3; ++dr) {
            const int hh = h + dr - 1;
            const bool rv = (hh >= 0) && (hh < IMH);
            const float* xr2 = x + ((size_t)(b * CH + ch) * IMH + (rv ? hh : 0)) * IMW;
            if (rv) {
                const float4 m4 = *(const float4*)(xr2 + wb);
                xv[dr][1] = m4.x; xv[dr][2] = m4.y; xv[dr][3] = m4.z; xv[dr][4] = m4.w;
                xv[dr][0] = (wb > 0)       ? xr2[wb - 1] : 0.0f;
                xv[dr][5] = (wb + 4 < IMW) ? xr2[wb + 4] : 0.0f;
            } else {
                #pragma unroll
                for (int j = 0; j < 6; ++j) xv[dr][j] = 0.0f;
            }
        }
        float o[4] = {0.0f, 0.0f, 0.0f, 0.0f};
        #pragma unroll
        for (int k = 0; k < 9; ++k) {
            const int dr = k / 3, dc = k % 3;
            const uint2 kk = *(const uint2*)(kerL + (cb + k) * KLS2 + tn * 4);
            const unsigned short* ks = (const unsigned short*)&kk;
            #pragma unroll
            for (int j = 0; j < 4; ++j)
                o[j] += b2f(ks[j]) * xv[dr][j + dc];
        }
        float4 ov = {o[0], o[1], o[2], o[3]};
        *(float4*)(out + ((size_t)(b * CH + ch) * IMH + h) * IMW + wb) = ov;
    }
}

// ---------------------------------------------------------------------------
extern "C" void kernel_launch(void* const* d_in, const int* in_sizes, int n_in,
                              void* d_out, int out_size, void* d_ws, size_t ws_size,
                              hipStream_t stream) {
    const float* x     = (const float*)d_in[0];
    const float* Wi    = (const float*)d_in[1];
    const float* bi    = (const float*)d_in[2];
    const float* gamma = (const float*)d_in[3];
    const float* beta  = (const float*)d_in[4];
    const float* Wo    = (const float*)d_in[5];
    const float* bo    = (const float*)d_in[6];
    float* out = (float*)d_out;

    char* ws = (char*)d_ws;
    unsigned short* xt  = (unsigned short*)(ws + XT_OFF);
    unsigned short* Wib = (unsigned short*)(ws + WIB_OFF);
    unsigned short* Wos = (unsigned short*)(ws + WOS_OFF);
    float* slots = (float*)(ws + WOS_OFF);      // stat slots + counter, pre-fold
    float* bo2   = (float*)(ws + BO2_OFF);

    k_pre<<<dim3(HW / 64, CH / 32, NB), 256, 0, stream>>>(x, xt, Wi, Wib, slots);
    k_gemm1<<<dim3(NBLK1), 256, 0, stream>>>(Wib, bi, xt, slots,
                                             gamma, beta, Wo, bo, Wos, bo2);
    k_gemm2_invol<<<dim3(HW / 64, NB), 256, 0, stream>>>(xt, Wos, bo2, x, out);
}

// Round 10
// 198.586 us; speedup vs baseline: 1.2190x; 1.0538x over previous
//
#include <hip/hip_runtime.h>

#define CH   288
#define GRPS 32
#define CPG  9
#define IMH  64
#define IMW  64
#define HW   4096
#define NB   8
#define NPX  (NB * HW)     // 32768 total pixel rows
#define BN_EPS 1e-5f
#define NSLOT 64

typedef short bf16x8 __attribute__((ext_vector_type(8)));
typedef float f32x4  __attribute__((ext_vector_type(4)));

// ws layout (bytes)
#define XT_OFF   0u            // x_t / tmp_t bf16 [b][p][c]  (18,874,368 B)
#define WIB_OFF  18874368u     // WibF bf16 fragment-tiled [162][1024 B]
#define WOS_OFF  19040256u     // WosF bf16 fragment-tiled; ALSO stat slots
                               //   (64 x 576 f32) before k_fold overwrites
#define SC_OFF   19208448u     // scale f32 [288]
#define SH_OFF   19209600u     // shift f32 [288]
#define BO2_OFF  19210752u     // folded bias f32 [288]

// Fragment-tiled W layout (both WibF and WosF):
//   tile T = jt*9 + kk,  jt = ch-tile (0..17), kk = K-step (0..8)
//   byte off = T*1024 + lane*16, lane = q*16 + r
//   holds bf16 W[jt*16 + r][kk*32 + q*8 .. +8]
// -> a wave's MFMA A-fragment load is ONE coalesced 1-KB dwordx4 (L2-hot).

__device__ __forceinline__ unsigned short f2b(float f) {
    unsigned int u = __float_as_uint(f);
    return (unsigned short)((u + 0x7fffu + ((u >> 16) & 1u)) >> 16);
}
__device__ __forceinline__ float b2f(unsigned short h) {
    return __uint_as_float(((unsigned int)h) << 16);
}

// async global->LDS, 16B per lane; dst = wave-uniform base + lane*16
#define GLDS(g, l) __builtin_amdgcn_global_load_lds( \
    (const __attribute__((address_space(1))) void*)(g), \
    (__attribute__((address_space(3))) void*)(l), 16, 0, 0)

__device__ __forceinline__ f32x4 mfma16(bf16x8 a, bf16x8 b, f32x4 c) {
    return __builtin_amdgcn_mfma_f32_16x16x32_bf16(a, b, c, 0, 0, 0);
}

// Stage a 32-px x full-K x-tile (18,432 B contiguous rows) into LDS with the
// XOR chunk swizzle applied via per-lane source addressing (R3-proven pair).
#define STAGE_X32(XSRC) do {                                                   \
    for (int s = wave; s < 18; s += 4) {                                       \
        const int d   = s * 1024 + lane * 16;                                  \
        const int px  = d / 576;                                               \
        const int rem = d - px * 576;                                          \
        const int kc  = rem >> 6;                                              \
        const int ch  = (rem >> 4) & 3;                                        \
        const int sc  = ch ^ ((px >> 1) & 3);                                  \
        GLDS((XSRC) + (size_t)px * CH + kc * 32 + sc * 8, smc + s * 1024);     \
    }                                                                          \
} while (0)

// ---------------------------------------------------------------------------
// K0: fused pre-pass.
//  - all blocks: x [b][c][p] f32 -> x_t [b][p][c] bf16
//  - blocks (y==0,z==0): zero the 64 stat slots
//  - blocks (y==1,z==0): Wi f32 -> WibF (fragment-tiled bf16)
// ---------------------------------------------------------------------------
#define TS 40
__global__ __launch_bounds__(256) void k_pre(const float* __restrict__ x,
                                             unsigned short* __restrict__ xt,
                                             const float* __restrict__ Wi,
                                             unsigned short* __restrict__ WibF,
                                             float* __restrict__ slots) {
    __shared__ unsigned short T[64 * TS];
    const int tid = threadIdx.x;
    const int p0 = blockIdx.x * 64;
    const int c0 = blockIdx.y * 32;
    const int b  = blockIdx.z;

    if (blockIdx.z == 0) {
        if (blockIdx.y == 0) {
            for (int i = blockIdx.x * 256 + tid; i < NSLOT * 576; i += 64 * 256)
                slots[i] = 0.0f;
        } else if (blockIdx.y == 1) {
            // WibF: 162 tiles x 64 lanes, one 16-B chunk per item
            for (int id = blockIdx.x * 256 + tid; id < 162 * 64; id += 64 * 256) {
                const int t    = id >> 6;
                const int lane = id & 63;
                const int q    = lane >> 4;
                const int r    = lane & 15;
                const int jt   = t / 9;
                const int kk   = t - jt * 9;
                const int row  = jt * 16 + r;
                const int k0   = kk * 32 + q * 8;
                const float4 a = *(const float4*)(Wi + (size_t)row * CH + k0);
                const float4 bq = *(const float4*)(Wi + (size_t)row * CH + k0 + 4);
                unsigned short h[8] = {f2b(a.x), f2b(a.y), f2b(a.z), f2b(a.w),
                                       f2b(bq.x), f2b(bq.y), f2b(bq.z), f2b(bq.w)};
                *(uint4*)(WibF + (size_t)t * 512 + lane * 8) = *(const uint4*)h;
            }
        }
    }

    #pragma unroll
    for (int it = 0; it < 2; ++it) {
        const int item  = it * 256 + tid;
        const int c_loc = item >> 4;
        const int p4    = item & 15;
        const float4 v = *(const float4*)(x + (size_t)(b * CH + c0 + c_loc) * HW + p0 + p4 * 4);
        const int px = p4 * 4;
        T[(px + 0) * TS + c_loc] = f2b(v.x);
        T[(px + 1) * TS + c_loc] = f2b(v.y);
        T[(px + 2) * TS + c_loc] = f2b(v.z);
        T[(px + 3) * TS + c_loc] = f2b(v.w);
    }
    __syncthreads();
    const int px_loc = tid >> 2;
    const int cq     = tid & 3;
    const uint4 o = *(const uint4*)((const char*)T + px_loc * (TS * 2) + cq * 16);
    *(uint4*)(xt + ((size_t)b * HW + p0 + px_loc) * CH + c0 + cq * 8) = o;
}

// ---------------------------------------------------------------------------
// K1: BARRIER-FREE MFMA GEMM1 + fused BN stats.
//   tmp_t[px][c] = relu(dot(x_t[px][:], Wi[c][:]) + bi[c])  (bf16, in-place)
// Block: 32 px x 288 c (full-ch -> in-place safe), 4 waves;
// wave = 16 px x 144 c (acc[9]).
// x-tile staged ONCE (18 KB LDS, one __syncthreads); W streamed to registers
// as coalesced 1-KB fragment loads from WibF (L2-hot). K-loop: 81 independent
// loads + 81 MFMA, ZERO barriers -> compiler pipelines with counted vmcnt.
// ---------------------------------------------------------------------------
__global__ __launch_bounds__(256) void k_gemm1(const unsigned short* __restrict__ WibF,
                                               const float* __restrict__ bi,
                                               unsigned short* __restrict__ xt,
                                               float* __restrict__ slots) {
    __shared__ char smc[20736];   // 18,432 staging / 18,432+2,304 epilogue

    const int tid  = threadIdx.x;
    const int wave = tid >> 6;
    const int lane = tid & 63;
    const int q    = lane >> 4;
    const int r    = lane & 15;
    const int pxh  = wave & 1;      // 16-px half
    const int chh  = wave >> 1;     // 144-c half
    const int p0   = blockIdx.x * 32;

    f32x4 acc[9];
    #pragma unroll
    for (int j = 0; j < 9; ++j) acc[j] = (f32x4)0.0f;

    STAGE_X32(xt + (size_t)p0 * CH);
    asm volatile("s_waitcnt vmcnt(0)" ::: "memory");
    __syncthreads();

    // ---- barrier-free K-loop ----
    #pragma unroll
    for (int kk = 0; kk < 9; ++kk) {
        const int xr = pxh * 16 + r;
        const bf16x8 xf = *(const bf16x8*)(smc + xr * 576 + kk * 64 +
                                           ((q ^ ((xr >> 1) & 3)) * 16));
        #pragma unroll
        for (int j = 0; j < 9; ++j) {
            const bf16x8 wf = *(const bf16x8*)(WibF +
                (size_t)((chh * 9 + j) * 9 + kk) * 512 + lane * 8);
            acc[j] = mfma16(wf, xf, acc[j]);
        }
    }
    __syncthreads();

    // ================= epilogue (R5-proven) =================
    // LDS reuse: [0, 18432) = 32 rows x 576 B output staging,
    //            [18432, 20736) = 576-float stats accumulator.
    float* sstat = (float*)(smc + 18432);
    for (int c2 = tid; c2 < 576; c2 += 256) sstat[c2] = 0.0f;
    __syncthreads();

    #pragma unroll 1
    for (int j = 0; j < 9; ++j) {
        const int cb = chh * 144 + j * 16 + q * 4;
        const float4 b4 = *(const float4*)(bi + cb);
        float v[4];
        v[0] = fmaxf(acc[j][0] + b4.x, 0.0f);
        v[1] = fmaxf(acc[j][1] + b4.y, 0.0f);
        v[2] = fmaxf(acc[j][2] + b4.z, 0.0f);
        v[3] = fmaxf(acc[j][3] + b4.w, 0.0f);
        unsigned short h[4] = {f2b(v[0]), f2b(v[1]), f2b(v[2]), f2b(v[3])};
        *(uint2*)(smc + (pxh * 16 + r) * 576 + cb * 2) = *(const uint2*)h;
        float a1[4] = {v[0], v[1], v[2], v[3]};
        float a2[4] = {v[0]*v[0], v[1]*v[1], v[2]*v[2], v[3]*v[3]};
        #pragma unroll
        for (int m = 1; m < 16; m <<= 1) {
            #pragma unroll
            for (int i = 0; i < 4; ++i) {
                a1[i] += __shfl_xor(a1[i], m, 64);
                a2[i] += __shfl_xor(a2[i], m, 64);
            }
        }
        if (r == 0) {
            #pragma unroll
            for (int i = 0; i < 4; ++i) {
                atomicAdd(&sstat[cb + i], a1[i]);
                atomicAdd(&sstat[288 + cb + i], a2[i]);
            }
        }
    }
    __syncthreads();

    for (int idx = tid; idx < 1152; idx += 256) {
        const int row = idx / 36;
        const int off = idx - row * 36;
        *(uint4*)(xt + (size_t)(p0 + row) * CH + off * 8) =
            *(const uint4*)(smc + row * 576 + off * 16);
    }
    float* slot = slots + (size_t)(blockIdx.x & (NSLOT - 1)) * 576;
    for (int c2 = tid; c2 < 576; c2 += 256)
        atomicAdd(&slot[c2], sstat[c2]);
}

// ---------------------------------------------------------------------------
// K2a: reduce 64 stat slots -> BN scale/shift. 576 threads (9 waves).
// ---------------------------------------------------------------------------
__global__ __launch_bounds__(576) void k_scale(const float* __restrict__ slots,
                                               const float* __restrict__ gamma,
                                               const float* __restrict__ beta,
                                               float* __restrict__ scale,
                                               float* __restrict__ shift) {
    __shared__ float red[576];
    const int tid = threadIdx.x;
    float s = 0.0f;
    #pragma unroll 4
    for (int sl = 0; sl < NSLOT; ++sl) s += slots[sl * 576 + tid];
    red[tid] = s;
    __syncthreads();
    if (tid < CH) {
        const float inv  = 1.0f / (float)(NB * HW);
        const float mean = red[tid] * inv;
        const float var  = red[288 + tid] * inv - mean * mean;
        const float rs   = rsqrtf(var + BN_EPS);
        const float sc   = gamma[tid] * rs;
        scale[tid] = sc;
        shift[tid] = beta[tid] - mean * sc;
    }
}

// ---------------------------------------------------------------------------
// K2b: WosF[frag-tiled] = bf16(Wo*scale); bo2[m] = bo[m] + Wo[m][:]@shift
// (overwrites the stat slots -- runs after k_scale)
// ---------------------------------------------------------------------------
__global__ __launch_bounds__(64) void k_fold(const float* __restrict__ Wo,
                                             const float* __restrict__ bo,
                                             const float* __restrict__ scale,
                                             const float* __restrict__ shift,
                                             unsigned short* __restrict__ WosF,
                                             float* __restrict__ bo2) {
    const int m = blockIdx.x;
    const int t = threadIdx.x;
    float s = 0.0f;
    for (int k = t; k < CH; k += 64) s += Wo[(size_t)m * CH + k] * shift[k];
    #pragma unroll
    for (int off = 32; off > 0; off >>= 1) s += __shfl_down(s, off, 64);
    if (t == 0) bo2[m] = bo[m] + s;

    if (t < 36) {
        const int kk = t >> 2;
        const int q  = t & 3;
        const int jt = m >> 4;
        const int rr = m & 15;
        const int k0 = kk * 32 + q * 8;
        unsigned short h[8];
        #pragma unroll
        for (int j = 0; j < 8; ++j)
            h[j] = f2b(Wo[(size_t)m * CH + k0 + j] * scale[k0 + j]);
        *(uint4*)(WosF + (size_t)(jt * 9 + kk) * 512 + (q * 16 + rr) * 8) =
            *(const uint4*)h;
    }
}

// ---------------------------------------------------------------------------
// K3: BARRIER-FREE MFMA GEMM2 (ker = Wos @ tmp + bo2) -> kerL -> involution.
// Block: 32 px x 288 ker-ch, 4 waves; wave = 16 px x 144 c (acc[9]).
// Same structure as K1; involution epilogue is the R4-proven 32-px version.
// ---------------------------------------------------------------------------
#define KLS 36
__global__ __launch_bounds__(256) void k_gemm2_invol(const unsigned short* __restrict__ xt,
                                                     const unsigned short* __restrict__ WosF,
                                                     const float* __restrict__ bo2,
                                                     const float* __restrict__ x,
                                                     float* __restrict__ out) {
    __shared__ char smc[20736];   // 18,432 staging / 20,736 kerL
    unsigned short* kerL = (unsigned short*)smc;

    const int tid  = threadIdx.x;
    const int wave = tid >> 6;
    const int lane = tid & 63;
    const int q    = lane >> 4;
    const int r    = lane & 15;
    const int pxh  = wave & 1;
    const int chh  = wave >> 1;
    const int p0   = blockIdx.x * 32;
    const int b    = blockIdx.y;
    const int h    = p0 >> 6;
    const int w0   = p0 & 63;
    const size_t rowbase = (size_t)b * HW + p0;

    f32x4 acc[9];
    #pragma unroll
    for (int j = 0; j < 9; ++j) acc[j] = (f32x4)0.0f;

    STAGE_X32(xt + rowbase * CH);
    asm volatile("s_waitcnt vmcnt(0)" ::: "memory");
    __syncthreads();

    #pragma unroll
    for (int kk = 0; kk < 9; ++kk) {
        const int xr = pxh * 16 + r;
        const bf16x8 xf = *(const bf16x8*)(smc + xr * 576 + kk * 64 +
                                           ((q ^ ((xr >> 1) & 3)) * 16));
        #pragma unroll
        for (int j = 0; j < 9; ++j) {
            const bf16x8 wf = *(const bf16x8*)(WosF +
                (size_t)((chh * 9 + j) * 9 + kk) * 512 + lane * 8);
            acc[j] = mfma16(wf, xf, acc[j]);
        }
    }
    __syncthreads();

    // ---- stage ker tile to LDS: kerL[ch][px], 288 x 32 (stride 36) ----
    const int pxl = pxh * 16 + r;
    #pragma unroll
    for (int j = 0; j < 9; ++j) {
        const int cb = chh * 144 + j * 16 + q * 4;
        const float4 bz = *(const float4*)(bo2 + cb);
        kerL[(cb + 0) * KLS + pxl] = f2b(acc[j][0] + bz.x);
        kerL[(cb + 1) * KLS + pxl] = f2b(acc[j][1] + bz.y);
        kerL[(cb + 2) * KLS + pxl] = f2b(acc[j][2] + bz.z);
        kerL[(cb + 3) * KLS + pxl] = f2b(acc[j][3] + bz.w);
    }
    __syncthreads();

    // ---- involution: 256 threads, 32 ch x 32 w per iteration, 9 iters ----
    const int tm = tid >> 3;
    const int tn = tid & 7;
    const int wb = w0 + tn * 4;
    #pragma unroll 1
    for (int i = 0; i < 9; ++i) {
        const int ch = tm + 32 * i;
        const int cb = (ch / CPG) * CPG;
        float xv[3][6];
        #pragma unroll
        for (int dr = 0; dr < 3; ++dr) {
            const int hh = h + dr - 1;
            const bool rv = (hh >= 0) && (hh < IMH);
            const float* xr2 = x + ((size_t)(b * CH + ch) * IMH + (rv ? hh : 0)) * IMW;
            if (rv) {
                const float4 m4 = *(const float4*)(xr2 + wb);
                xv[dr][1] = m4.x; xv[dr][2] = m4.y; xv[dr][3] = m4.z; xv[dr][4] = m4.w;
                xv[dr][0] = (wb > 0)       ? xr2[wb - 1] : 0.0f;
                xv[dr][5] = (wb + 4 < IMW) ? xr2[wb + 4] : 0.0f;
            } else {
                #pragma unroll
                for (int j = 0; j < 6; ++j) xv[dr][j] = 0.0f;
            }
        }
        float o[4] = {0.0f, 0.0f, 0.0f, 0.0f};
        #pragma unroll
        for (int k = 0; k < 9; ++k) {
            const int dr = k / 3, dc = k % 3;
            const uint2 kk = *(const uint2*)(kerL + (cb + k) * KLS + tn * 4);
            const unsigned short* ks = (const unsigned short*)&kk;
            #pragma unroll
            for (int j = 0; j < 4; ++j)
                o[j] += b2f(ks[j]) * xv[dr][j + dc];
        }
        float4 ov = {o[0], o[1], o[2], o[3]};
        *(float4*)(out + ((size_t)(b * CH + ch) * IMH + h) * IMW + wb) = ov;
    }
}

// ---------------------------------------------------------------------------
extern "C" void kernel_launch(void* const* d_in, const int* in_sizes, int n_in,
                              void* d_out, int out_size, void* d_ws, size_t ws_size,
                              hipStream_t stream) {
    const float* x     = (const float*)d_in[0];
    const float* Wi    = (const float*)d_in[1];
    const float* bi    = (const float*)d_in[2];
    const float* gamma = (const float*)d_in[3];
    const float* beta  = (const float*)d_in[4];
    const float* Wo    = (const float*)d_in[5];
    const float* bo    = (const float*)d_in[6];
    float* out = (float*)d_out;

    char* ws = (char*)d_ws;
    unsigned short* xt   = (unsigned short*)(ws + XT_OFF);
    unsigned short* WibF = (unsigned short*)(ws + WIB_OFF);
    unsigned short* WosF = (unsigned short*)(ws + WOS_OFF);
    float* slots = (float*)(ws + WOS_OFF);      // stat slots, pre-k_fold
    float* scale = (float*)(ws + SC_OFF);
    float* shift = (float*)(ws + SH_OFF);
    float* bo2   = (float*)(ws + BO2_OFF);

    k_pre<<<dim3(HW / 64, CH / 32, NB), 256, 0, stream>>>(x, xt, Wi, WibF, slots);
    k_gemm1<<<dim3(NPX / 32), 256, 0, stream>>>(WibF, bi, xt, slots);
    k_scale<<<dim3(1), 576, 0, stream>>>(slots, gamma, beta, scale, shift);
    k_fold<<<dim3(CH), 64, 0, stream>>>(Wo, bo, scale, shift, WosF, bo2);
    k_gemm2_invol<<<dim3(HW / 32, NB), 256, 0, stream>>>(xt, WosF, bo2, x, out);
}

// Round 12
// 190.330 us; speedup vs baseline: 1.2719x; 1.0434x over previous
//
#include <hip/hip_runtime.h>

#define CH   288
#define GRPS 32
#define CPG  9
#define IMH  64
#define IMW  64
#define HW   4096
#define NB   8
#define NPX  (NB * HW)     // 32768 total pixel rows
#define BN_EPS 1e-5f
#define NSLOT 64

typedef short bf16x8 __attribute__((ext_vector_type(8)));
typedef float f32x4  __attribute__((ext_vector_type(4)));

// ws layout (bytes)
#define TMP_OFF  0u            // tmp bf16 [b][p][c]  (18,874,368 B)
#define WIB_OFF  18874368u     // WibF bf16 fragment-tiled [162][1024 B]
#define WOS_OFF  19040256u     // WosF bf16 fragment-tiled; ALSO stat slots
                               //   (64 x 576 f32) before k_fold overwrites
#define SC_OFF   19208448u     // scale f32 [288]
#define SH_OFF   19209600u     // shift f32 [288]
#define BO2_OFF  19210752u     // folded bias f32 [288]

// Fragment-tiled W layout (both WibF and WosF):
//   tile T = jt*9 + kk,  jt = ch-tile (0..17), kk = K-step (0..8)
//   byte off = T*1024 + lane*16, lane = q*16 + r
//   holds bf16 W[jt*16 + r][kk*32 + q*8 .. +8]

__device__ __forceinline__ unsigned short f2b(float f) {
    unsigned int u = __float_as_uint(f);
    return (unsigned short)((u + 0x7fffu + ((u >> 16) & 1u)) >> 16);
}
__device__ __forceinline__ float b2f(unsigned short h) {
    return __uint_as_float(((unsigned int)h) << 16);
}

// async global->LDS, 16B per lane; dst = wave-uniform base + lane*16
#define GLDS(g, l) __builtin_amdgcn_global_load_lds( \
    (const __attribute__((address_space(1))) void*)(g), \
    (__attribute__((address_space(3))) void*)(l), 16, 0, 0)

__device__ __forceinline__ f32x4 mfma16(bf16x8 a, bf16x8 b, f32x4 c) {
    return __builtin_amdgcn_mfma_f32_16x16x32_bf16(a, b, c, 0, 0, 0);
}

// Stage a 32-px x full-K bf16 tile (18,432 B contiguous rows) into LDS with
// the XOR chunk swizzle applied via per-lane source addressing.
#define STAGE_X32(XSRC) do {                                                   \
    for (int s = wave; s < 18; s += 4) {                                       \
        const int d   = s * 1024 + lane * 16;                                  \
        const int px  = d / 576;                                               \
        const int rem = d - px * 576;                                          \
        const int kc  = rem >> 6;                                              \
        const int ch  = (rem >> 4) & 3;                                        \
        const int sc  = ch ^ ((px >> 1) & 3);                                  \
        GLDS((XSRC) + (size_t)px * CH + kc * 32 + sc * 8, smc + s * 1024);     \
    }                                                                          \
} while (0)

// ---------------------------------------------------------------------------
// K0: WibF conversion + stat-slot zeroing (single small dispatch, 64 blocks)
// ---------------------------------------------------------------------------
__global__ __launch_bounds__(256) void k_cvt(const float* __restrict__ Wi,
                                             unsigned short* __restrict__ WibF,
                                             float* __restrict__ slots) {
    const int id = blockIdx.x * 256 + threadIdx.x;
    if (id < 162 * 64) {
        const int t    = id >> 6;
        const int lane = id & 63;
        const int q    = lane >> 4;
        const int r    = lane & 15;
        const int jt   = t / 9;
        const int kk   = t - jt * 9;
        const int row  = jt * 16 + r;
        const int k0   = kk * 32 + q * 8;
        const float4 a  = *(const float4*)(Wi + (size_t)row * CH + k0);
        const float4 bq = *(const float4*)(Wi + (size_t)row * CH + k0 + 4);
        unsigned short h[8] = {f2b(a.x), f2b(a.y), f2b(a.z), f2b(a.w),
                               f2b(bq.x), f2b(bq.y), f2b(bq.z), f2b(bq.w)};
        *(uint4*)(WibF + (size_t)t * 512 + lane * 8) = *(const uint4*)h;
    }
    for (int i = id; i < NSLOT * 576; i += 64 * 256) slots[i] = 0.0f;
}

// ---------------------------------------------------------------------------
// K1: BARRIER-FREE MFMA GEMM1 + fused BN stats, reading x DIRECTLY (f32).
//   tmp[px][c] = relu(dot(x[px][:], Wi[c][:]) + bi[c])  (bf16 out)
// Block: 32 px x 288 c, 4 waves; wave = 16 px x 144 c (acc[9]).
// x-tile staged once as f32 [288 ch][32 px] (36,864 B LDS; each ch row is a
// contiguous 128-B run of x -> per-lane-source GLDS). Fragments built by
// 8x ds_read_b32 + inline f2b (identical values to the old k_pre path).
// W streamed to registers as coalesced 1-KB fragment loads (L2-hot).
// Eliminates the k_pre transpose kernel entirely.
// ---------------------------------------------------------------------------
__global__ __launch_bounds__(256) void k_gemm1(const unsigned short* __restrict__ WibF,
                                               const float* __restrict__ bi,
                                               const float* __restrict__ x,
                                               unsigned short* __restrict__ tmp,
                                               float* __restrict__ slots) {
    __shared__ char smc[36864];   // f32 x-tile / epilogue reuse

    const int tid  = threadIdx.x;
    const int wave = tid >> 6;
    const int lane = tid & 63;
    const int q    = lane >> 4;
    const int r    = lane & 15;
    const int pxh  = wave & 1;      // 16-px half
    const int chh  = wave >> 1;     // 144-c half
    const int p0   = blockIdx.x * 32;
    const int b    = p0 >> 12;      // batch
    const int pi   = p0 & 4095;     // pixel base within image

    f32x4 acc[9];
    #pragma unroll
    for (int j = 0; j < 9; ++j) acc[j] = (f32x4)0.0f;

    // ---- stage x f32 tile: 36 segments x 1 KB; seg s lane l covers
    //      ch = s*8 + (l>>3), px-offset (l&7)*4 (16 B = 4 f32) ----
    for (int s = wave; s < 36; s += 4) {
        const int ch  = s * 8 + (lane >> 3);
        const int pxo = (lane & 7) * 4;
        GLDS(x + (size_t)(b * CH + ch) * HW + pi + pxo, smc + s * 1024);
    }
    asm volatile("s_waitcnt vmcnt(0)" ::: "memory");
    __syncthreads();

    // ---- barrier-free K-loop ----
    const float* xl = (const float*)smc;   // [ch][32] f32
    #pragma unroll
    for (int kk = 0; kk < 9; ++kk) {
        const int px = pxh * 16 + r;
        unsigned short hh[8];
        #pragma unroll
        for (int j = 0; j < 8; ++j)
            hh[j] = f2b(xl[(kk * 32 + q * 8 + j) * 32 + px]);
        const bf16x8 xf = *(const bf16x8*)hh;
        #pragma unroll
        for (int j = 0; j < 9; ++j) {
            const bf16x8 wf = *(const bf16x8*)(WibF +
                (size_t)((chh * 9 + j) * 9 + kk) * 512 + lane * 8);
            acc[j] = mfma16(wf, xf, acc[j]);
        }
    }
    __syncthreads();

    // ================= epilogue (R5-proven) =================
    // LDS reuse: [0, 18432) = 32 rows x 576 B output staging,
    //            [18432, 20736) = 576-float stats accumulator.
    float* sstat = (float*)(smc + 18432);
    for (int c2 = tid; c2 < 576; c2 += 256) sstat[c2] = 0.0f;
    __syncthreads();

    #pragma unroll 1
    for (int j = 0; j < 9; ++j) {
        const int cb = chh * 144 + j * 16 + q * 4;
        const float4 b4 = *(const float4*)(bi + cb);
        float v[4];
        v[0] = fmaxf(acc[j][0] + b4.x, 0.0f);
        v[1] = fmaxf(acc[j][1] + b4.y, 0.0f);
        v[2] = fmaxf(acc[j][2] + b4.z, 0.0f);
        v[3] = fmaxf(acc[j][3] + b4.w, 0.0f);
        unsigned short h[4] = {f2b(v[0]), f2b(v[1]), f2b(v[2]), f2b(v[3])};
        *(uint2*)(smc + (pxh * 16 + r) * 576 + cb * 2) = *(const uint2*)h;
        float a1[4] = {v[0], v[1], v[2], v[3]};
        float a2[4] = {v[0]*v[0], v[1]*v[1], v[2]*v[2], v[3]*v[3]};
        #pragma unroll
        for (int m = 1; m < 16; m <<= 1) {
            #pragma unroll
            for (int i = 0; i < 4; ++i) {
                a1[i] += __shfl_xor(a1[i], m, 64);
                a2[i] += __shfl_xor(a2[i], m, 64);
            }
        }
        if (r == 0) {
            #pragma unroll
            for (int i = 0; i < 4; ++i) {
                atomicAdd(&sstat[cb + i], a1[i]);
                atomicAdd(&sstat[288 + cb + i], a2[i]);
            }
        }
    }
    __syncthreads();

    for (int idx = tid; idx < 1152; idx += 256) {
        const int row = idx / 36;
        const int off = idx - row * 36;
        *(uint4*)(tmp + (size_t)(p0 + row) * CH + off * 8) =
            *(const uint4*)(smc + row * 576 + off * 16);
    }
    float* slot = slots + (size_t)(blockIdx.x & (NSLOT - 1)) * 576;
    for (int c2 = tid; c2 < 576; c2 += 256)
        atomicAdd(&slot[c2], sstat[c2]);
}

// ---------------------------------------------------------------------------
// K2a: reduce 64 stat slots -> BN scale/shift. 576 threads (9 waves).
// ---------------------------------------------------------------------------
__global__ __launch_bounds__(576) void k_scale(const float* __restrict__ slots,
                                               const float* __restrict__ gamma,
                                               const float* __restrict__ beta,
                                               float* __restrict__ scale,
                                               float* __restrict__ shift) {
    __shared__ float red[576];
    const int tid = threadIdx.x;
    float s = 0.0f;
    #pragma unroll 4
    for (int sl = 0; sl < NSLOT; ++sl) s += slots[sl * 576 + tid];
    red[tid] = s;
    __syncthreads();
    if (tid < CH) {
        const float inv  = 1.0f / (float)(NB * HW);
        const float mean = red[tid] * inv;
        const float var  = red[288 + tid] * inv - mean * mean;
        const float rs   = rsqrtf(var + BN_EPS);
        const float sc   = gamma[tid] * rs;
        scale[tid] = sc;
        shift[tid] = beta[tid] - mean * sc;
    }
}

// ---------------------------------------------------------------------------
// K2b: WosF[frag-tiled] = bf16(Wo*scale); bo2[m] = bo[m] + Wo[m][:]@shift
// (overwrites the stat slots -- runs after k_scale)
// ---------------------------------------------------------------------------
__global__ __launch_bounds__(64) void k_fold(const float* __restrict__ Wo,
                                             const float* __restrict__ bo,
                                             const float* __restrict__ scale,
                                             const float* __restrict__ shift,
                                             unsigned short* __restrict__ WosF,
                                             float* __restrict__ bo2) {
    const int m = blockIdx.x;
    const int t = threadIdx.x;
    float s = 0.0f;
    for (int k = t; k < CH; k += 64) s += Wo[(size_t)m * CH + k] * shift[k];
    #pragma unroll
    for (int off = 32; off > 0; off >>= 1) s += __shfl_down(s, off, 64);
    if (t == 0) bo2[m] = bo[m] + s;

    if (t < 36) {
        const int kk = t >> 2;
        const int q  = t & 3;
        const int jt = m >> 4;
        const int rr = m & 15;
        const int k0 = kk * 32 + q * 8;
        unsigned short h[8];
        #pragma unroll
        for (int j = 0; j < 8; ++j)
            h[j] = f2b(Wo[(size_t)m * CH + k0 + j] * scale[k0 + j]);
        *(uint4*)(WosF + (size_t)(jt * 9 + kk) * 512 + (q * 16 + rr) * 8) =
            *(const uint4*)h;
    }
}

// ---------------------------------------------------------------------------
// K3: BARRIER-FREE MFMA GEMM2 -> kerL -> involution, with bijective
// XCD-chunked block swizzle: sw = (bid&7)*128 + (bid>>3) maps all 128 blocks
// of image b to XCD b -> the involution's h-1/h/h+1 x-row re-reads become
// per-XCD L2 hits (R10 FETCH showed ~2x x over-fetch from cross-XCD spread).
// Block: 32 px x 288 ker-ch, 4 waves; wave = 16 px x 144 c (acc[9]).
// ---------------------------------------------------------------------------
#define KLS 36
__global__ __launch_bounds__(256) void k_gemm2_invol(const unsigned short* __restrict__ tmp,
                                                     const unsigned short* __restrict__ WosF,
                                                     const float* __restrict__ bo2,
                                                     const float* __restrict__ x,
                                                     float* __restrict__ out) {
    __shared__ char smc[20736];   // 18,432 staging / 20,736 kerL
    unsigned short* kerL = (unsigned short*)smc;

    const int tid  = threadIdx.x;
    const int wave = tid >> 6;
    const int lane = tid & 63;
    const int q    = lane >> 4;
    const int r    = lane & 15;
    const int pxh  = wave & 1;
    const int chh  = wave >> 1;

    const int bid = blockIdx.x;                 // flat 0..1023
    const int sw  = (bid & 7) * 128 + (bid >> 3);
    const int b   = sw >> 7;                    // image (== XCD id)
    const int p0  = (sw & 127) * 32;            // px within image
    const int h   = p0 >> 6;
    const int w0  = p0 & 63;
    const size_t rowbase = (size_t)b * HW + p0;

    f32x4 acc[9];
    #pragma unroll
    for (int j = 0; j < 9; ++j) acc[j] = (f32x4)0.0f;

    STAGE_X32(tmp + rowbase * CH);
    asm volatile("s_waitcnt vmcnt(0)" ::: "memory");
    __syncthreads();

    #pragma unroll
    for (int kk = 0; kk < 9; ++kk) {
        const int xr = pxh * 16 + r;
        const bf16x8 xf = *(const bf16x8*)(smc + xr * 576 + kk * 64 +
                                           ((q ^ ((xr >> 1) & 3)) * 16));
        #pragma unroll
        for (int j = 0; j < 9; ++j) {
            const bf16x8 wf = *(const bf16x8*)(WosF +
                (size_t)((chh * 9 + j) * 9 + kk) * 512 + lane * 8);
            acc[j] = mfma16(wf, xf, acc[j]);
        }
    }
    __syncthreads();

    // ---- stage ker tile to LDS: kerL[ch][px], 288 x 32 (stride 36) ----
    const int pxl = pxh * 16 + r;
    #pragma unroll
    for (int j = 0; j < 9; ++j) {
        const int cb = chh * 144 + j * 16 + q * 4;
        const float4 bz = *(const float4*)(bo2 + cb);
        kerL[(cb + 0) * KLS + pxl] = f2b(acc[j][0] + bz.x);
        kerL[(cb + 1) * KLS + pxl] = f2b(acc[j][1] + bz.y);
        kerL[(cb + 2) * KLS + pxl] = f2b(acc[j][2] + bz.z);
        kerL[(cb + 3) * KLS + pxl] = f2b(acc[j][3] + bz.w);
    }
    __syncthreads();

    // ---- involution: 256 threads, 32 ch x 32 w per iteration, 9 iters ----
    const int tm = tid >> 3;
    const int tn = tid & 7;
    const int wb = w0 + tn * 4;
    #pragma unroll 1
    for (int i = 0; i < 9; ++i) {
        const int ch = tm + 32 * i;
        const int cb = (ch / CPG) * CPG;
        float xv[3][6];
        #pragma unroll
        for (int dr = 0; dr < 3; ++dr) {
            const int hh = h + dr - 1;
            const bool rv = (hh >= 0) && (hh < IMH);
            const float* xr2 = x + ((size_t)(b * CH + ch) * IMH + (rv ? hh : 0)) * IMW;
            if (rv) {
                const float4 m4 = *(const float4*)(xr2 + wb);
                xv[dr][1] = m4.x; xv[dr][2] = m4.y; xv[dr][3] = m4.z; xv[dr][4] = m4.w;
                xv[dr][0] = (wb > 0)       ? xr2[wb - 1] : 0.0f;
                xv[dr][5] = (wb + 4 < IMW) ? xr2[wb + 4] : 0.0f;
            } else {
                #pragma unroll
                for (int j = 0; j < 6; ++j) xv[dr][j] = 0.0f;
            }
        }
        float o[4] = {0.0f, 0.0f, 0.0f, 0.0f};
        #pragma unroll
        for (int k = 0; k < 9; ++k) {
            const int dr = k / 3, dc = k % 3;
            const uint2 kk = *(const uint2*)(kerL + (cb + k) * KLS + tn * 4);
            const unsigned short* ks = (const unsigned short*)&kk;
            #pragma unroll
            for (int j = 0; j < 4; ++j)
                o[j] += b2f(ks[j]) * xv[dr][j + dc];
        }
        float4 ov = {o[0], o[1], o[2], o[3]};
        *(float4*)(out + ((size_t)(b * CH + ch) * IMH + h) * IMW + wb) = ov;
    }
}

// ---------------------------------------------------------------------------
extern "C" void kernel_launch(void* const* d_in, const int* in_sizes, int n_in,
                              void* d_out, int out_size, void* d_ws, size_t ws_size,
                              hipStream_t stream) {
    const float* x     = (const float*)d_in[0];
    const float* Wi    = (const float*)d_in[1];
    const float* bi    = (const float*)d_in[2];
    const float* gamma = (const float*)d_in[3];
    const float* beta  = (const float*)d_in[4];
    const float* Wo    = (const float*)d_in[5];
    const float* bo    = (const float*)d_in[6];
    float* out = (float*)d_out;

    char* ws = (char*)d_ws;
    unsigned short* tmp  = (unsigned short*)(ws + TMP_OFF);
    unsigned short* WibF = (unsigned short*)(ws + WIB_OFF);
    unsigned short* WosF = (unsigned short*)(ws + WOS_OFF);
    float* slots = (float*)(ws + WOS_OFF);      // stat slots, pre-k_fold
    float* scale = (float*)(ws + SC_OFF);
    float* shift = (float*)(ws + SH_OFF);
    float* bo2   = (float*)(ws + BO2_OFF);

    k_cvt<<<dim3(64), 256, 0, stream>>>(Wi, WibF, slots);
    k_gemm1<<<dim3(NPX / 32), 256, 0, stream>>>(WibF, bi, x, tmp, slots);
    k_scale<<<dim3(1), 576, 0, stream>>>(slots, gamma, beta, scale, shift);
    k_fold<<<dim3(CH), 64, 0, stream>>>(Wo, bo, scale, shift, WosF, bo2);
    k_gemm2_invol<<<dim3(NPX / 32), 256, 0, stream>>>(tmp, WosF, bo2, x, out);
}